// Round 5
// baseline (157.514 us; speedup 1.0000x reference)
//
#include <hip/hip_runtime.h>

#define B 64
#define N 1024
#define G 256
#define H 512

// exp(-50*d^2) = 2^(-72.134752*d^2); pre-scale plane coeffs by sqrt(72.134752)
#define S_SCALE 8.4932183f
#define INV_S   (1.0f / S_SCALE)

__device__ __forceinline__ float exp2_fast(float x) {
#if __has_builtin(__builtin_amdgcn_exp2f)
    return __builtin_amdgcn_exp2f(x);   // raw v_exp_f32
#else
    return __expf(x * 0.69314718056f);  // e^(x ln2) = 2^x
#endif
}

// ---------------------------------------------------------------------------
// Kernel 1: stable top-k (k=G=256) of pt_weight per batch via O(N^2) ranking.
// 4 blocks per batch (256 threads each); thread ranks one element against all
// N via broadcast float4 LDS reads.
// rank_i = #{ j : w_j > w_i  or (w_j == w_i and j < i) }  -> exact lax.top_k
// order (descending value, ties broken by lower index). Also zeroes the
// per-batch finalize counter for kernel 2.
// ---------------------------------------------------------------------------
#define TKB 4  // blocks per batch

__global__ __launch_bounds__(256) void topk_gather_kernel(
    const float* __restrict__ pts,        // (B,3,N)
    const float* __restrict__ pt_weight,  // (B,N)
    float* __restrict__ out_gpts,         // (B,G,3)
    int* __restrict__ cnt)                // (B) finalize counters, zeroed here
{
    const int b = blockIdx.x / TKB;
    const int q = blockIdx.x % TKB;

    __shared__ float w[N];
    ((float4*)w)[threadIdx.x] = ((const float4*)(pt_weight + (size_t)b * N))[threadIdx.x];
    if (q == 0 && threadIdx.x == 0) cnt[b] = 0;
    __syncthreads();

    const int i = q * 256 + threadIdx.x;
    const float wi = w[i];

    int rank = 0;
#pragma unroll 8
    for (int j = 0; j < N; j += 4) {
        const float4 wj = *(const float4*)(w + j);  // broadcast LDS read
        rank += (wj.x > wi) || (wj.x == wi && (j + 0) < i);
        rank += (wj.y > wi) || (wj.y == wi && (j + 1) < i);
        rank += (wj.z > wi) || (wj.z == wi && (j + 2) < i);
        rank += (wj.w > wi) || (wj.w == wi && (j + 3) < i);
    }

    if (rank < G) {
        float* dst = out_gpts + ((size_t)b * G + rank) * 3;
        dst[0] = pts[b * 3 * N + 0 * N + i];
        dst[1] = pts[b * 3 * N + 1 * N + i];
        dst[2] = pts[b * 3 * N + 2 * N + i];
    }
}

// ---------------------------------------------------------------------------
// Kernel 2: plane + score + loss, then last-block-per-batch finalize (argmax,
// softmax, exp_loss, top_loss, pred) — no grid sync: the last block of each
// batch (device-scope atomic counter) does the reduction.
// One block = one batch x 32 hypotheses; pts[b] (12KB) + gpts[b] (3KB) in LDS.
// Each wave evaluates its 8 hypotheses per point-load (LDS reads amortized).
// NOTE: the hypothesis-setup loop MUST be fully unrolled — partial unroll
// makes hh a runtime index and demotes nx/ny/nz/pd/acc to scratch (r4: 138us,
// VGPR=44).
// ---------------------------------------------------------------------------
union SMem {
    struct { float sp[3 * N]; float gp[3 * G]; } p2;      // 15.4 KB
    struct { float v[4]; int idx[4]; float sw[4]; float swl[4];
             float smax; int smaxi; } p3;
};

__global__ __launch_bounds__(256) void plane_finalize_kernel(
    const float* __restrict__ pts,      // (B,3,N)
    const float* __restrict__ target,   // (B,3)
    const int* __restrict__ sel_idx,    // (B,H,3)
    float* __restrict__ out,            // exp_loss(B)|top_loss(B)|pred(3B)|gpts(B,G,3)
    float* __restrict__ score,          // ws (B,H)
    float* __restrict__ loss,           // ws (B,H)
    float* __restrict__ normals,        // ws (B,H,3)
    int* __restrict__ cnt)              // ws (B)
{
    __shared__ SMem sm;
    __shared__ bool s_last;
    const int blk = blockIdx.x;
    const int tid = threadIdx.x;
    const int b   = blk >> 4;   // 64 batches
    const int hg  = blk & 15;   // 16 hypothesis-groups per batch
    const int wave = tid >> 6;
    const int lane = tid & 63;
    const float* gpts = out + 5 * B;  // gathered points written by kernel 1

    // ---------------- stage pts + gpts into LDS ----------------
    {
        const float4* ps = (const float4*)(pts + (size_t)b * 3 * N);
        float4* spv = (float4*)sm.p2.sp;
        spv[tid]       = ps[tid];
        spv[tid + 256] = ps[tid + 256];
        spv[tid + 512] = ps[tid + 512];
        if (tid < 192)
            ((float4*)sm.p2.gp)[tid] =
                ((const float4*)(gpts + (size_t)b * 3 * G))[tid];
    }
    __syncthreads();

    // ---------------- plane + score + loss ----------------
    {
        const int h0 = (hg << 5) + (wave << 3);  // 32 hyps/block, 8/wave
        float nx[8], ny[8], nz[8], pd[8], acc[8];

        #pragma unroll   // FULL unroll: hh must be compile-time (rule #20)
        for (int hh = 0; hh < 8; ++hh) {
            const int* si = sel_idx + ((size_t)b * H + h0 + hh) * 3;
            const int g0 = si[0] * 3, g1 = si[1] * 3, g2 = si[2] * 3;
            const float p0x = sm.p2.gp[g0], p0y = sm.p2.gp[g0 + 1], p0z = sm.p2.gp[g0 + 2];
            const float p1x = sm.p2.gp[g1], p1y = sm.p2.gp[g1 + 1], p1z = sm.p2.gp[g1 + 2];
            const float p2x = sm.p2.gp[g2], p2y = sm.p2.gp[g2 + 1], p2z = sm.p2.gp[g2 + 2];
            const float e1x = p1x - p0x, e1y = p1y - p0y, e1z = p1z - p0z;
            const float e2x = p2x - p0x, e2y = p2y - p0y, e2z = p2z - p0z;
            float x = e1y * e2z - e1z * e2y;
            float y = e1z * e2x - e1x * e2z;
            float z = e1x * e2y - e1y * e2x;
            float d = -(x * p0x + y * p0y + z * p0z);
            if (x == 0.f && y == 0.f && z == 0.f && d == 0.f) { x = y = z = d = 1.f; }
            const float ns = S_SCALE / sqrtf(x * x + y * y + z * z);
            nx[hh] = x * ns; ny[hh] = y * ns; nz[hh] = z * ns; pd[hh] = d * ns;
            acc[hh] = 0.f;
        }

        #pragma unroll 4
        for (int k = 0; k < N / 64; ++k) {
            const int n = lane + (k << 6);
            const float px = sm.p2.sp[n], py = sm.p2.sp[N + n], pz = sm.p2.sp[2 * N + n];
            #pragma unroll
            for (int hh = 0; hh < 8; ++hh) {
                const float u = fmaf(nx[hh], px, fmaf(ny[hh], py, fmaf(nz[hh], pz, pd[hh])));
                acc[hh] += exp2_fast(-(u * u));  // neg folds into v_exp src modifier
            }
        }

        const float tx = target[b * 3 + 0], ty = target[b * 3 + 1], tz = target[b * 3 + 2];
        #pragma unroll
        for (int hh = 0; hh < 8; ++hh) {
            float a = acc[hh];
            #pragma unroll
            for (int off = 32; off; off >>= 1) a += __shfl_xor(a, off);
            if (lane == 0) {
                const float x = nx[hh] * INV_S, y = ny[hh] * INV_S, z = nz[hh] * INV_S;
                const float l1 = (x - tx) * (x - tx) + (y - ty) * (y - ty) + (z - tz) * (z - tz);
                const float l2 = (x + tx) * (x + tx) + (y + ty) * (y + ty) + (z + tz) * (z + tz);
                const int idx = b * H + h0 + hh;
                score[idx] = a;
                loss[idx] = fminf(l1, l2);
                normals[idx * 3 + 0] = x;
                normals[idx * 3 + 1] = y;
                normals[idx * 3 + 2] = z;
            }
        }
    }

    // ---------------- last block of batch b finalizes ----------------
    __threadfence();           // release: publish score/loss/normals
    __syncthreads();
    if (tid == 0) s_last = (atomicAdd(&cnt[b], 1) == 15);
    __syncthreads();
    if (!s_last) return;
    __threadfence();           // acquire: see all 16 blocks' writes

    {
        const float* sc = score + b * H;
        const float* ls = loss + b * H;
        const float s0 = sc[tid], s1 = sc[tid + 256];

        float v; int vi;
        if (s1 > s0) { v = s1; vi = tid + 256; } else { v = s0; vi = tid; }
        #pragma unroll
        for (int off = 32; off; off >>= 1) {
            const float v2 = __shfl_xor(v, off);
            const int i2 = __shfl_xor(vi, off);
            if (v2 > v || (v2 == v && i2 < vi)) { v = v2; vi = i2; }
        }
        if (lane == 0) { sm.p3.v[wave] = v; sm.p3.idx[wave] = vi; }
        __syncthreads();
        if (tid == 0) {
            float bv = sm.p3.v[0]; int bi = sm.p3.idx[0];
            #pragma unroll
            for (int k = 1; k < 4; ++k) {
                if (sm.p3.v[k] > bv || (sm.p3.v[k] == bv && sm.p3.idx[k] < bi)) {
                    bv = sm.p3.v[k]; bi = sm.p3.idx[k];
                }
            }
            sm.p3.smax = bv; sm.p3.smaxi = bi;
        }
        __syncthreads();
        const float m = sm.p3.smax;
        const float w0 = __expf(0.5f * (s0 - m)), w1 = __expf(0.5f * (s1 - m));
        float tw = w0 + w1;
        float twl = w0 * ls[tid] + w1 * ls[tid + 256];
        #pragma unroll
        for (int off = 32; off; off >>= 1) {
            tw += __shfl_xor(tw, off);
            twl += __shfl_xor(twl, off);
        }
        if (lane == 0) { sm.p3.sw[wave] = tw; sm.p3.swl[wave] = twl; }
        __syncthreads();
        if (tid == 0) {
            const float TW = sm.p3.sw[0] + sm.p3.sw[1] + sm.p3.sw[2] + sm.p3.sw[3];
            const float TWL = sm.p3.swl[0] + sm.p3.swl[1] + sm.p3.swl[2] + sm.p3.swl[3];
            const int mi = sm.p3.smaxi;
            out[b] = TWL / TW;                               // exp_loss
            out[B + b] = ls[mi];                             // top_loss
            out[2 * B + b * 3 + 0] = normals[((size_t)b * H + mi) * 3 + 0];
            out[2 * B + b * 3 + 1] = normals[((size_t)b * H + mi) * 3 + 1];
            out[2 * B + b * 3 + 2] = normals[((size_t)b * H + mi) * 3 + 2];
        }
    }
}

// ---------------------------------------------------------------------------
extern "C" void kernel_launch(void* const* d_in, const int* in_sizes, int n_in,
                              void* d_out, int out_size, void* d_ws, size_t ws_size,
                              hipStream_t stream) {
    const float* pts       = (const float*)d_in[0];  // (B,3,N)
    const float* target    = (const float*)d_in[1];  // (B,3)
    const float* pt_weight = (const float*)d_in[2];  // (B,N)
    const int*   sel_idx   = (const int*)d_in[3];    // (B,H,3)

    float* out = (float*)d_out;
    // layout: exp_loss[B] | top_loss[B] | pred[B*3] | gpts[B*G*3]
    float* out_gpts = out + 5 * B;

    float* ws      = (float*)d_ws;
    float* score   = ws;                      // B*H
    float* loss    = ws + B * H;              // B*H
    float* normals = ws + 2 * B * H;          // B*H*3
    int*   cnt     = (int*)(ws + 5 * B * H);  // B

    topk_gather_kernel<<<B * TKB, 256, 0, stream>>>(pts, pt_weight, out_gpts, cnt);
    plane_finalize_kernel<<<B * 16, 256, 0, stream>>>(pts, target, sel_idx, out,
                                                      score, loss, normals, cnt);
}

// Round 6
// 51.307 us; speedup vs baseline: 3.0700x; 3.0700x over previous
//
#include <hip/hip_runtime.h>

#define B 64
#define N 1024
#define G 256
#define H 512

// exp(-50*d^2) = 2^(-72.134752*d^2); pre-scale plane coeffs by sqrt(72.134752)
#define S_SCALE 8.4932183f
#define INV_S   (1.0f / S_SCALE)

__device__ __forceinline__ float exp2_fast(float x) {
#if __has_builtin(__builtin_amdgcn_exp2f)
    return __builtin_amdgcn_exp2f(x);   // raw v_exp_f32
#else
    return __expf(x * 0.69314718056f);  // e^(x ln2) = 2^x
#endif
}

// ---------------------------------------------------------------------------
// Kernel 1: stable top-k (k=G=256) of pt_weight per batch via O(N^2) ranking.
// 4 blocks per batch (256 threads each); thread ranks one element against all
// N via broadcast float4 LDS reads.
// rank_i = #{ j : w_j > w_i  or (w_j == w_i and j < i) }  -> exact lax.top_k
// order (descending value, ties broken by lower index).
// NO fences/atomics anywhere: kernel boundaries are the synchronization
// (r3-r5 lesson: __threadfence() on 8-XCD gfx950 = cross-L2 maintenance,
// ~100us of stall across 1024 blocks).
// ---------------------------------------------------------------------------
#define TKB 4  // blocks per batch

__global__ __launch_bounds__(256) void topk_gather_kernel(
    const float* __restrict__ pts,        // (B,3,N)
    const float* __restrict__ pt_weight,  // (B,N)
    float* __restrict__ out_gpts)         // (B,G,3)
{
    const int b = blockIdx.x / TKB;
    const int q = blockIdx.x % TKB;

    __shared__ float w[N];
    ((float4*)w)[threadIdx.x] = ((const float4*)(pt_weight + (size_t)b * N))[threadIdx.x];
    __syncthreads();

    const int i = q * 256 + threadIdx.x;
    const float wi = w[i];

    int rank = 0;
#pragma unroll 8
    for (int j = 0; j < N; j += 4) {
        const float4 wj = *(const float4*)(w + j);  // broadcast LDS read
        rank += (wj.x > wi) || (wj.x == wi && (j + 0) < i);
        rank += (wj.y > wi) || (wj.y == wi && (j + 1) < i);
        rank += (wj.z > wi) || (wj.z == wi && (j + 2) < i);
        rank += (wj.w > wi) || (wj.w == wi && (j + 3) < i);
    }

    if (rank < G) {
        float* dst = out_gpts + ((size_t)b * G + rank) * 3;
        dst[0] = pts[b * 3 * N + 0 * N + i];
        dst[1] = pts[b * 3 * N + 1 * N + i];
        dst[2] = pts[b * 3 * N + 2 * N + i];
    }
}

// ---------------------------------------------------------------------------
// Kernel 2: per hypothesis: plane from 3 gathered points, normalize, score =
// sum_n exp(-50*dist^2), loss = min(||n-t||^2, ||n+t||^2).
// One block = one batch x 32 hypotheses; pts[b] (12KB) + gpts[b] (3KB) in LDS.
// Each wave evaluates 8 hypotheses per point-load; inner-loop live set
// nx/ny/nz/pd/acc[8]+n,px,py,pz = 44 VGPR exactly (register-resident, r5).
// ---------------------------------------------------------------------------
__global__ __launch_bounds__(256) void plane_score_kernel(
    const float* __restrict__ pts,      // (B,3,N)
    const float* __restrict__ target,   // (B,3)
    const int* __restrict__ sel_idx,    // (B,H,3)
    const float* __restrict__ gpts,     // (B,G,3) [in d_out, from kernel 1]
    float* __restrict__ score,          // ws (B,H)
    float* __restrict__ loss,           // ws (B,H)
    float* __restrict__ normals)        // ws (B,H,3)
{
    __shared__ float sp[3 * N];   // 12 KB
    __shared__ float gp[3 * G];   // 3 KB
    const int blk = blockIdx.x;
    const int tid = threadIdx.x;
    const int b   = blk >> 4;   // 64 batches
    const int hg  = blk & 15;   // 16 hypothesis-groups per batch
    const int wave = tid >> 6;
    const int lane = tid & 63;

    {
        const float4* ps = (const float4*)(pts + (size_t)b * 3 * N);
        float4* spv = (float4*)sp;
        spv[tid]       = ps[tid];
        spv[tid + 256] = ps[tid + 256];
        spv[tid + 512] = ps[tid + 512];
        if (tid < 192)
            ((float4*)gp)[tid] = ((const float4*)(gpts + (size_t)b * 3 * G))[tid];
    }
    __syncthreads();

    const int h0 = (hg << 5) + (wave << 3);  // 32 hyps/block, 8/wave
    float nx[8], ny[8], nz[8], pd[8], acc[8];

    #pragma unroll
    for (int hh = 0; hh < 8; ++hh) {
        const int* si = sel_idx + ((size_t)b * H + h0 + hh) * 3;
        const int g0 = si[0] * 3, g1 = si[1] * 3, g2 = si[2] * 3;
        const float p0x = gp[g0], p0y = gp[g0 + 1], p0z = gp[g0 + 2];
        const float p1x = gp[g1], p1y = gp[g1 + 1], p1z = gp[g1 + 2];
        const float p2x = gp[g2], p2y = gp[g2 + 1], p2z = gp[g2 + 2];
        const float e1x = p1x - p0x, e1y = p1y - p0y, e1z = p1z - p0z;
        const float e2x = p2x - p0x, e2y = p2y - p0y, e2z = p2z - p0z;
        float x = e1y * e2z - e1z * e2y;
        float y = e1z * e2x - e1x * e2z;
        float z = e1x * e2y - e1y * e2x;
        float d = -(x * p0x + y * p0y + z * p0z);
        if (x == 0.f && y == 0.f && z == 0.f && d == 0.f) { x = y = z = d = 1.f; }
        const float ns = S_SCALE / sqrtf(x * x + y * y + z * z);
        nx[hh] = x * ns; ny[hh] = y * ns; nz[hh] = z * ns; pd[hh] = d * ns;
        acc[hh] = 0.f;
    }

    #pragma unroll 4
    for (int k = 0; k < N / 64; ++k) {
        const int n = lane + (k << 6);
        const float px = sp[n], py = sp[N + n], pz = sp[2 * N + n];
        #pragma unroll
        for (int hh = 0; hh < 8; ++hh) {
            const float u = fmaf(nx[hh], px, fmaf(ny[hh], py, fmaf(nz[hh], pz, pd[hh])));
            acc[hh] += exp2_fast(-(u * u));  // neg folds into v_exp src modifier
        }
    }

    const float tx = target[b * 3 + 0], ty = target[b * 3 + 1], tz = target[b * 3 + 2];
    #pragma unroll
    for (int hh = 0; hh < 8; ++hh) {
        float a = acc[hh];
        #pragma unroll
        for (int off = 32; off; off >>= 1) a += __shfl_xor(a, off);
        if (lane == 0) {
            const float x = nx[hh] * INV_S, y = ny[hh] * INV_S, z = nz[hh] * INV_S;
            const float l1 = (x - tx) * (x - tx) + (y - ty) * (y - ty) + (z - tz) * (z - tz);
            const float l2 = (x + tx) * (x + tx) + (y + ty) * (y + ty) + (z + tz) * (z + tz);
            const int idx = b * H + h0 + hh;
            score[idx] = a;
            loss[idx] = fminf(l1, l2);
            normals[idx * 3 + 0] = x;
            normals[idx * 3 + 1] = y;
            normals[idx * 3 + 2] = z;
        }
    }
}

// ---------------------------------------------------------------------------
// Kernel 3: per batch: argmax(score) (tie -> first idx), stable softmax of
// 0.5*score, exp_loss = sum(loss*w)/sum(w), top_loss, pred.
// 256 threads handle 2 hypotheses each; wave-shuffle reductions.
// ---------------------------------------------------------------------------
__global__ __launch_bounds__(256) void finalize_kernel(
    const float* __restrict__ score,    // (B,H)
    const float* __restrict__ loss,     // (B,H)
    const float* __restrict__ normals,  // (B,H,3)
    float* __restrict__ out)            // exp_loss(B)|top_loss(B)|pred(3B)|gpts...
{
    const int b = blockIdx.x;
    const int tid = threadIdx.x;
    const int wave = tid >> 6;
    const int lane = tid & 63;

    __shared__ float sv[4]; __shared__ int sidx[4];
    __shared__ float ssw[4], sswl[4];
    __shared__ float s_max; __shared__ int s_maxi;

    const float* sc = score + b * H;
    const float* ls = loss + b * H;
    const float s0 = sc[tid], s1 = sc[tid + 256];

    float v; int vi;
    if (s1 > s0) { v = s1; vi = tid + 256; } else { v = s0; vi = tid; }
    #pragma unroll
    for (int off = 32; off; off >>= 1) {
        const float v2 = __shfl_xor(v, off);
        const int i2 = __shfl_xor(vi, off);
        if (v2 > v || (v2 == v && i2 < vi)) { v = v2; vi = i2; }
    }
    if (lane == 0) { sv[wave] = v; sidx[wave] = vi; }
    __syncthreads();

    if (tid == 0) {
        float bv = sv[0]; int bi = sidx[0];
        #pragma unroll
        for (int k = 1; k < 4; ++k) {
            if (sv[k] > bv || (sv[k] == bv && sidx[k] < bi)) { bv = sv[k]; bi = sidx[k]; }
        }
        s_max = bv; s_maxi = bi;
    }
    __syncthreads();

    const float m = s_max;
    const float w0 = __expf(0.5f * (s0 - m)), w1 = __expf(0.5f * (s1 - m));
    float tw = w0 + w1;
    float twl = w0 * ls[tid] + w1 * ls[tid + 256];
    #pragma unroll
    for (int off = 32; off; off >>= 1) {
        tw += __shfl_xor(tw, off);
        twl += __shfl_xor(twl, off);
    }
    if (lane == 0) { ssw[wave] = tw; sswl[wave] = twl; }
    __syncthreads();

    if (tid == 0) {
        const float TW = ssw[0] + ssw[1] + ssw[2] + ssw[3];
        const float TWL = sswl[0] + sswl[1] + sswl[2] + sswl[3];
        const int mi = s_maxi;
        out[b] = TWL / TW;                               // exp_loss
        out[B + b] = ls[mi];                             // top_loss
        out[2 * B + b * 3 + 0] = normals[((size_t)b * H + mi) * 3 + 0];
        out[2 * B + b * 3 + 1] = normals[((size_t)b * H + mi) * 3 + 1];
        out[2 * B + b * 3 + 2] = normals[((size_t)b * H + mi) * 3 + 2];
    }
}

// ---------------------------------------------------------------------------
extern "C" void kernel_launch(void* const* d_in, const int* in_sizes, int n_in,
                              void* d_out, int out_size, void* d_ws, size_t ws_size,
                              hipStream_t stream) {
    const float* pts       = (const float*)d_in[0];  // (B,3,N)
    const float* target    = (const float*)d_in[1];  // (B,3)
    const float* pt_weight = (const float*)d_in[2];  // (B,N)
    const int*   sel_idx   = (const int*)d_in[3];    // (B,H,3)

    float* out = (float*)d_out;
    // layout: exp_loss[B] | top_loss[B] | pred[B*3] | gpts[B*G*3]
    float* out_gpts = out + 5 * B;

    float* ws      = (float*)d_ws;
    float* score   = ws;                      // B*H
    float* loss    = ws + B * H;              // B*H
    float* normals = ws + 2 * B * H;          // B*H*3

    topk_gather_kernel<<<B * TKB, 256, 0, stream>>>(pts, pt_weight, out_gpts);
    plane_score_kernel<<<B * 16, 256, 0, stream>>>(pts, target, sel_idx, out_gpts,
                                                   score, loss, normals);
    finalize_kernel<<<B, 256, 0, stream>>>(score, loss, normals, out);
}